// Round 1
// baseline (2105.242 us; speedup 1.0000x reference)
//
#include <hip/hip_runtime.h>
#include <cmath>

#define Ncnt 6000
#define Ecnt 192000
#define INF_ 19900
#define HID  16

// ---- workspace layout (float offsets) ----
#define OFF_SEDGE   0        // 8   : edge_input col sums/sumsq
#define OFF_HSUM    8        // 256 : h batch sums   [side*128+k]
#define OFF_HSQ     264      // 256 : h batch sumsq
#define OFF_DEG     520      // 6000: weighted degree (edge part)
#define OFF_BNSUM   6520     // 64  : per-layer BN sums  [l*16+c]
#define OFF_BNSQ    6584     // 64
#define OFF_XW      6648     // 96000 : x @ W  (layer-0 accumulates atomically -> must be zero)
#define OFF_XBUF    102648   // 4*96000 : per-layer outputs
#define ZERO_FLOATS 486648
#define OFF_MU      486648   // 4
#define OFF_SDINV   486652   // 4
#define OFF_WSM     486656   // 4 (+pad)
#define OFF_HSCALE  486660   // 256
#define OFF_HSHIFT  486916   // 256
#define OFF_DINV    487172   // 6000
#define OFF_EW      493172   // 192000

__device__ __forceinline__ float4 f4add(float4 a, float4 b) {
  return make_float4(a.x+b.x, a.y+b.y, a.z+b.z, a.w+b.w);
}

// ---- edge_input column stats (sum, sumsq) ----
__global__ void k_estats(const float* __restrict__ ei, float* __restrict__ S) {
  __shared__ float4 r1[256], r2[256];
  int t = threadIdx.x;
  float4 s = make_float4(0,0,0,0), q = make_float4(0,0,0,0);
  for (int i = blockIdx.x*256 + t; i < Ecnt; i += gridDim.x*256) {
    float4 v = ((const float4*)ei)[i];
    s.x += v.x; s.y += v.y; s.z += v.z; s.w += v.w;
    q.x += v.x*v.x; q.y += v.y*v.y; q.z += v.z*v.z; q.w += v.w*v.w;
  }
  r1[t] = s; r2[t] = q; __syncthreads();
  for (int st = 128; st > 0; st >>= 1) {
    if (t < st) { r1[t] = f4add(r1[t], r1[t+st]); r2[t] = f4add(r2[t], r2[t+st]); }
    __syncthreads();
  }
  if (t == 0) {
    atomicAdd(&S[0], r1[0].x); atomicAdd(&S[1], r1[0].y);
    atomicAdd(&S[2], r1[0].z); atomicAdd(&S[3], r1[0].w);
    atomicAdd(&S[4], r2[0].x); atomicAdd(&S[5], r2[0].y);
    atomicAdd(&S[6], r2[0].z); atomicAdd(&S[7], r2[0].w);
  }
}

// ---- finalize edge stats (ddof=1 std) + softmax(layer_w) ----
__global__ void k_finalize_a(const float* __restrict__ S, const float* __restrict__ lw,
                             float* __restrict__ mu, float* __restrict__ sdinv,
                             float* __restrict__ wsm) {
  int t = threadIdx.x;
  if (t < 4) {
    float s = S[t], q = S[4+t];
    float m = s / (float)Ecnt;
    float var = (q - s*s/(float)Ecnt) / (float)(Ecnt - 1);
    mu[t] = m;
    sdinv[t] = rsqrtf(var);
  }
  if (t == 0) {
    float l0 = lw[0], l1 = lw[1], l2 = lw[2], l3 = lw[3];
    float mx = fmaxf(fmaxf(l0,l1), fmaxf(l2,l3));
    float e0 = expf(l0-mx), e1 = expf(l1-mx), e2 = expf(l2-mx), e3 = expf(l3-mx);
    float inv = 1.f/(e0+e1+e2+e3);
    wsm[0]=e0*inv; wsm[1]=e1*inv; wsm[2]=e2*inv; wsm[3]=e3*inv;
  }
}

// ---- batch stats of h = relu(z @ w1 + b1), both sides ----
__global__ void k_hstats(const float* __restrict__ ei, const float* __restrict__ w1,
                         const float* __restrict__ b1, const float* __restrict__ mu,
                         const float* __restrict__ sdinv,
                         float* __restrict__ hsum, float* __restrict__ hsq) {
  __shared__ float z[1024];
  int t = threadIdx.x;
  int e0 = blockIdx.x * 256;
  for (int i = 0; i < 4; ++i) z[i*256+t] = ei[e0*4 + i*256 + t];
  __syncthreads();
  int side = t >> 7, k = t & 127;
  float wa = w1[k], wb = w1[128+k], bb = b1[k];
  float m0 = mu[side*2], m1 = mu[side*2+1];
  float s0 = sdinv[side*2], s1 = sdinv[side*2+1];
  float sum = 0.f, sq = 0.f;
  for (int e = 0; e < 256; ++e) {
    float z0 = (z[e*4 + side*2]   - m0) * s0;
    float z1 = (z[e*4 + side*2+1] - m1) * s1;
    float h = fmaxf(z0*wa + z1*wb + bb, 0.f);
    sum += h; sq += h*h;
  }
  atomicAdd(&hsum[t], sum);
  atomicAdd(&hsq[t], sq);
}

// ---- fold BN into scale/shift: hn = h*scale + shift ----
__global__ void k_finalize_b(const float* __restrict__ hsum, const float* __restrict__ hsq,
                             const float* __restrict__ g, const float* __restrict__ b,
                             float* __restrict__ hscale, float* __restrict__ hshift) {
  int t = threadIdx.x;           // 256 = side*128+k
  int k = t & 127;
  float m = hsum[t] / (float)Ecnt;
  float var = hsq[t] / (float)Ecnt - m*m;
  float sc = g[k] * rsqrtf(var + 1e-5f);
  hscale[t] = sc;
  hshift[t] = b[k] - m*sc;
}

// ---- big edge kernel: o = hn @ w2 + b2 (both sides), cosine -> ew, deg atomics ----
__global__ __launch_bounds__(256) void k_edge(
    const float* __restrict__ ei, const int* __restrict__ eidx,
    const float* __restrict__ w1, const float* __restrict__ b1,
    const float* __restrict__ mu, const float* __restrict__ sdinv,
    const float* __restrict__ hscale, const float* __restrict__ hshift,
    const float* __restrict__ w2, const float* __restrict__ b2,
    float* __restrict__ ew, float* __restrict__ deg) {
  __shared__ float zl[128];
  __shared__ float hn[2][32*132];   // stride 132 -> conflict-free phase-2 reads
  int t = threadIdx.x;
  int e0 = blockIdx.x * 32;
  if (t < 32) ((float4*)zl)[t] = ((const float4*)ei)[e0 + t];
  __syncthreads();
  float mu0 = mu[0], mu1 = mu[1], mu2 = mu[2], mu3 = mu[3];
  float si0 = sdinv[0], si1 = sdinv[1], si2 = sdinv[2], si3 = sdinv[3];
  for (int it = 0; it < 16; ++it) {
    int idx = it*256 + t;
    int e = idx >> 7, k = idx & 127;
    float wa = w1[k], wb = w1[128+k], bb = b1[k];
    float za = (zl[e*4+0]-mu0)*si0, zb = (zl[e*4+1]-mu1)*si1;
    float zc = (zl[e*4+2]-mu2)*si2, zd = (zl[e*4+3]-mu3)*si3;
    float h1 = fmaxf(za*wa + zb*wb + bb, 0.f);
    float h2 = fmaxf(zc*wa + zd*wb + bb, 0.f);
    hn[0][e*132+k] = h1*hscale[k]     + hshift[k];
    hn[1][e*132+k] = h2*hscale[128+k] + hshift[128+k];
  }
  __syncthreads();
  int e = t >> 3, jg = t & 7, j0 = jg*16;
  float a1[16], a2[16];
  #pragma unroll
  for (int i = 0; i < 4; ++i) {
    float4 bv = ((const float4*)b2)[(j0>>2)+i];
    a1[4*i+0]=bv.x; a1[4*i+1]=bv.y; a1[4*i+2]=bv.z; a1[4*i+3]=bv.w;
    a2[4*i+0]=bv.x; a2[4*i+1]=bv.y; a2[4*i+2]=bv.z; a2[4*i+3]=bv.w;
  }
  const float4* w2v = (const float4*)w2;
  const float* h1p = &hn[0][e*132];
  const float* h2p = &hn[1][e*132];
  for (int k = 0; k < 128; ++k) {
    float s1 = h1p[k], s2 = h2p[k];
    int base = (k*128 + j0) >> 2;
    #pragma unroll
    for (int i = 0; i < 4; ++i) {
      float4 w = w2v[base + i];
      a1[4*i+0] += s1*w.x; a1[4*i+1] += s1*w.y; a1[4*i+2] += s1*w.z; a1[4*i+3] += s1*w.w;
      a2[4*i+0] += s2*w.x; a2[4*i+1] += s2*w.y; a2[4*i+2] += s2*w.z; a2[4*i+3] += s2*w.w;
    }
  }
  float d = 0.f, q1 = 0.f, q2 = 0.f;
  #pragma unroll
  for (int i = 0; i < 16; ++i) { d += a1[i]*a2[i]; q1 += a1[i]*a1[i]; q2 += a2[i]*a2[i]; }
  __syncthreads();
  float* red = &hn[0][0];
  red[t] = d; red[256+t] = q1; red[512+t] = q2;
  __syncthreads();
  if (t < 32) {
    float dd=0.f, qa=0.f, qb=0.f;
    #pragma unroll
    for (int i = 0; i < 8; ++i) {
      dd += red[t*8+i]; qa += red[256+t*8+i]; qb += red[512+t*8+i];
    }
    float nn = sqrtf(qa*qb);
    float c = dd / fmaxf(nn, 1e-8f);
    float w = 0.5f*(c + 1.f);
    ew[e0+t] = w;
    atomicAdd(&deg[eidx[Ecnt + e0 + t]], w);
  }
}

// ---- dinv = rsqrt(deg + 1)  (self-loop weight 1 folded in; deg>=1 always) ----
__global__ void k_dinv(const float* __restrict__ deg, float* __restrict__ dinv) {
  int n = blockIdx.x*256 + threadIdx.x;
  if (n < Ncnt) dinv[n] = rsqrtf(deg[n] + 1.0f);
}

// ---- layer-0 GEMM rewrite ----
// Tile: 64 rows x 128 k staged in LDS (stride 132 for conflict-free b128).
// Compute: lane == row, k wave-uniform -> w0 row loads are s_load (SGPR
// broadcast), emb via ds_read_b128 (lane stride 132 dwords = 4 mod 32 ->
// exactly 8 dwords/bank, conflict-free). Each of the 4 waves takes a
// k-quarter of the chunk; K further split 8-way over blockIdx.y; partials
// combined with atomicAdd into xw (zeroed by the memset).
#define G0_ROWS 64
#define G0_KC   128
#define G0_KSPLIT 8

__global__ __launch_bounds__(256) void k_gemm0(const float* __restrict__ emb,
                                               const float* __restrict__ w0,
                                               float* __restrict__ xw) {
  __shared__ float embL[G0_ROWS * 132];
  int t = threadIdx.x;
  int lane = t & 63, wv = t >> 6;
  int r0 = blockIdx.x * G0_ROWS;
  float acc[16];
  #pragma unroll
  for (int h = 0; h < 16; ++h) acc[h] = 0.f;

  for (int c = blockIdx.y; c * G0_KC < INF_; c += G0_KSPLIT) {
    int k0 = c * G0_KC;
    int klen = INF_ - k0; if (klen > G0_KC) klen = G0_KC;   // 128 or 60 (div by 4)
    __syncthreads();
    // stage 64 rows x klen floats, coalesced float4
    for (int i = t; i < G0_ROWS * (G0_KC/4); i += 256) {
      int rr = i >> 5;          // 32 float4 per row
      int ff = i & 31;
      float4 v = make_float4(0.f, 0.f, 0.f, 0.f);
      int gr = r0 + rr;
      if (gr >= Ncnt) gr = 0;   // valid address; result discarded at epilogue
      if (ff * 4 < klen) v = *(const float4*)(emb + (size_t)gr * INF_ + k0 + ff * 4);
      *(float4*)(embL + rr * 132 + ff * 4) = v;
    }
    __syncthreads();
    // wave wv computes k-quarter [wv*32, wv*32+32) (in float4 steps)
    int kqend = klen >> 2;
    int kqlo = wv * 8, kqhi = kqlo + 8;
    if (kqhi > kqend) kqhi = kqend;
    for (int kq = kqlo; kq < kqhi; ++kq) {
      float4 ev = *(const float4*)(embL + lane * 132 + kq * 4);
      const float* wr = w0 + (size_t)(k0 + kq * 4) * 16;   // wave-uniform -> s_load
      #pragma unroll
      for (int s = 0; s < 4; ++s) {
        float evs = (s == 0) ? ev.x : (s == 1) ? ev.y : (s == 2) ? ev.z : ev.w;
        #pragma unroll
        for (int h4 = 0; h4 < 4; ++h4) {
          float4 w = *(const float4*)(wr + s * 16 + h4 * 4);
          acc[h4*4+0] += evs * w.x; acc[h4*4+1] += evs * w.y;
          acc[h4*4+2] += evs * w.z; acc[h4*4+3] += evs * w.w;
        }
      }
    }
  }
  int gr = r0 + lane;
  if (gr < Ncnt) {
    #pragma unroll
    for (int h = 0; h < 16; ++h) atomicAdd(&xw[gr * 16 + h], acc[h]);
  }
}

// ---- scatter: xo[col] += dinv[row]*ew*dinv[col] * xw[row]  (+ self loops) ----
__global__ void k_scatter(const int* __restrict__ eidx, const float* __restrict__ ew,
                          const float* __restrict__ dinv, const float* __restrict__ xw,
                          float* __restrict__ xo) {
  int g = blockIdx.x*256 + threadIdx.x;
  if (g >= (Ecnt + Ncnt)*4) return;
  int ent = g >> 2, q = g & 3;
  int r, c; float w;
  if (ent < Ecnt) {
    r = eidx[ent]; c = eidx[Ecnt + ent];
    w = dinv[r] * ew[ent] * dinv[c];
  } else {
    int n = ent - Ecnt; r = n; c = n;
    float dv = dinv[n]; w = dv*dv;
  }
  float4 v = *(const float4*)(xw + r*16 + q*4);
  float* dst = xo + c*16 + q*4;
  atomicAdd(dst+0, w*v.x);
  atomicAdd(dst+1, w*v.y);
  atomicAdd(dst+2, w*v.z);
  atomicAdd(dst+3, w*v.w);
}

// ---- per-layer BN stats (per column sums over N) ----
__global__ void k_bnstats(const float* __restrict__ x, float* __restrict__ bsum,
                          float* __restrict__ bsq) {
  __shared__ float r1[256], r2[256];
  int t = threadIdx.x;
  float sum = 0.f, sq = 0.f;
  for (int i = blockIdx.x*256 + t; i < Ncnt*HID; i += gridDim.x*256) {
    float v = x[i]; sum += v; sq += v*v;
  }
  r1[t] = sum; r2[t] = sq; __syncthreads();
  for (int s = 128; s >= 16; s >>= 1) {
    if (t < s) { r1[t] += r1[t+s]; r2[t] += r2[t+s]; }
    __syncthreads();
  }
  if (t < 16) { atomicAdd(&bsum[t], r1[t]); atomicAdd(&bsq[t], r2[t]); }
}

// ---- apply BN + relu + residual (in place). gcn_b cancels through BN. ----
__global__ void k_apply(float* __restrict__ x, const float* __restrict__ prev,
                        const float* __restrict__ bsum, const float* __restrict__ bsq,
                        const float* __restrict__ g, const float* __restrict__ b) {
  int i = blockIdx.x*256 + threadIdx.x;      // grid 375 -> exactly 96000
  int c = i & 15;
  float m = bsum[c] * (1.f/Ncnt);
  float var = bsq[c] * (1.f/Ncnt) - m*m;
  float rs = rsqrtf(var + 1e-5f);
  float v = (x[i]-m)*rs*g[c] + b[c];
  v = fmaxf(v, 0.f);
  if (prev) v += 0.7f*prev[i];
  x[i] = v;
}

// ---- small 16x16 GEMM for layers 1..3 ----
__global__ void k_gemm_small(const float* __restrict__ xin, const float* __restrict__ wm,
                             float* __restrict__ xw) {
  __shared__ float lx[16][17], lw_[16][17];
  int t = threadIdx.x;
  int r = t >> 4, c = t & 15;
  lx[r][c]  = xin[(blockIdx.x*16 + r)*16 + c];
  lw_[r][c] = wm[r*16 + c];
  __syncthreads();
  float acc = 0.f;
  #pragma unroll
  for (int k = 0; k < 16; ++k) acc += lx[r][k] * lw_[k][c];
  xw[(blockIdx.x*16 + r)*16 + c] = acc;
}

// ---- final: out = (sum_i wsm[i]*x_i) @ proj_w + proj_b ----
__global__ void k_proj(const float* __restrict__ x0, const float* __restrict__ x1,
                       const float* __restrict__ x2, const float* __restrict__ x3,
                       const float* __restrict__ wsm, const float* __restrict__ pw,
                       const float* __restrict__ pb, float* __restrict__ out) {
  int n = blockIdx.x*256 + threadIdx.x;
  if (n >= Ncnt) return;
  float s0 = wsm[0], s1 = wsm[1], s2 = wsm[2], s3 = wsm[3];
  float a0 = pb[0], a1 = pb[1];
  #pragma unroll
  for (int h = 0; h < 16; ++h) {
    float e = s0*x0[n*16+h] + s1*x1[n*16+h] + s2*x2[n*16+h] + s3*x3[n*16+h];
    a0 += e * pw[h*2];
    a1 += e * pw[h*2+1];
  }
  out[n*2]   = a0;
  out[n*2+1] = a1;
}

extern "C" void kernel_launch(void* const* d_in, const int* in_sizes, int n_in,
                              void* d_out, int out_size, void* d_ws, size_t ws_size,
                              hipStream_t stream) {
  const float* emb   = (const float*)d_in[0];
  const int*   eidx  = (const int*)d_in[1];
  const float* einp  = (const float*)d_in[2];
  const float* e_w1  = (const float*)d_in[3];
  const float* e_b1  = (const float*)d_in[4];
  const float* e_bng = (const float*)d_in[5];
  const float* e_bnb = (const float*)d_in[6];
  const float* e_w2  = (const float*)d_in[7];
  const float* e_b2  = (const float*)d_in[8];
  const float* w0    = (const float*)d_in[9];
  const float* wrest = (const float*)d_in[10];
  // d_in[11] = gcn_b: provably cancels through training-mode BN (column shift)
  const float* bn_g  = (const float*)d_in[12];
  const float* bn_b  = (const float*)d_in[13];
  const float* lw    = (const float*)d_in[14];
  const float* pw    = (const float*)d_in[15];
  const float* pb    = (const float*)d_in[16];

  float* ws     = (float*)d_ws;
  float* S      = ws + OFF_SEDGE;
  float* hsum   = ws + OFF_HSUM;
  float* hsq    = ws + OFF_HSQ;
  float* deg    = ws + OFF_DEG;
  float* bnsum  = ws + OFF_BNSUM;
  float* bnsq   = ws + OFF_BNSQ;
  float* xw     = ws + OFF_XW;
  float* mu     = ws + OFF_MU;
  float* sdinv  = ws + OFF_SDINV;
  float* wsm    = ws + OFF_WSM;
  float* hscale = ws + OFF_HSCALE;
  float* hshift = ws + OFF_HSHIFT;
  float* dinv   = ws + OFF_DINV;
  float* ewb    = ws + OFF_EW;
  float* xb[4]  = { ws + OFF_XBUF, ws + OFF_XBUF + 96000,
                    ws + OFF_XBUF + 192000, ws + OFF_XBUF + 288000 };

  hipMemsetAsync(d_ws, 0, (size_t)ZERO_FLOATS * 4, stream);

  k_estats<<<188, 256, 0, stream>>>(einp, S);
  k_finalize_a<<<1, 64, 0, stream>>>(S, lw, mu, sdinv, wsm);
  k_hstats<<<750, 256, 0, stream>>>(einp, e_w1, e_b1, mu, sdinv, hsum, hsq);
  k_finalize_b<<<1, 256, 0, stream>>>(hsum, hsq, e_bng, e_bnb, hscale, hshift);
  k_edge<<<6000, 256, 0, stream>>>(einp, eidx, e_w1, e_b1, mu, sdinv,
                                   hscale, hshift, e_w2, e_b2, ewb, deg);
  k_dinv<<<24, 256, 0, stream>>>(deg, dinv);
  k_gemm0<<<dim3((Ncnt + G0_ROWS - 1)/G0_ROWS, G0_KSPLIT), 256, 0, stream>>>(emb, w0, xw);

  for (int l = 0; l < 4; ++l) {
    if (l > 0) k_gemm_small<<<375, 256, 0, stream>>>(xb[l-1], wrest + (l-1)*256, xw);
    k_scatter<<<3094, 256, 0, stream>>>(eidx, ewb, dinv, xw, xb[l]);
    k_bnstats<<<48, 256, 0, stream>>>(xb[l], bnsum + l*16, bnsq + l*16);
    k_apply<<<375, 256, 0, stream>>>(xb[l], (l > 0) ? xb[l-1] : (const float*)nullptr,
                                     bnsum + l*16, bnsq + l*16, bn_g + l*16, bn_b + l*16);
  }

  k_proj<<<24, 256, 0, stream>>>(xb[0], xb[1], xb[2], xb[3], wsm, pw, pb, (float*)d_out);
}

// Round 3
// 1579.147 us; speedup vs baseline: 1.3332x; 1.3332x over previous
//
#include <hip/hip_runtime.h>
#include <cmath>

#define Ncnt 6000
#define Ecnt 192000
#define INF_ 19900
#define HID  16

// ---- workspace layout (float offsets) ----
#define OFF_SEDGE   0        // 8   : edge_input col sums/sumsq
#define OFF_HSUM    8        // 256 : h batch sums   [side*128+k]
#define OFF_HSQ     264      // 256 : h batch sumsq
#define OFF_DEG     520      // 6000: weighted degree (edge part)
#define OFF_BNSUM   6520     // 64  : per-layer BN sums  [l*16+c]
#define OFF_BNSQ    6584     // 64
#define OFF_XW      6648     // 96000 : x @ W  (layer-0 accumulates atomically -> must be zero)
#define OFF_XBUF    102648   // 4*96000 : per-layer outputs
#define ZERO_FLOATS 486648
#define OFF_MU      486648   // 4
#define OFF_SDINV   486652   // 4
#define OFF_WSM     486656   // 4 (+pad)
#define OFF_HSCALE  486660   // 256
#define OFF_HSHIFT  486916   // 256
#define OFF_DINV    487172   // 6000
#define OFF_EW      493172   // 192000

__device__ __forceinline__ float4 f4add(float4 a, float4 b) {
  return make_float4(a.x+b.x, a.y+b.y, a.z+b.z, a.w+b.w);
}

// ---- edge_input column stats (sum, sumsq) ----
__global__ void k_estats(const float* __restrict__ ei, float* __restrict__ S) {
  __shared__ float4 r1[256], r2[256];
  int t = threadIdx.x;
  float4 s = make_float4(0,0,0,0), q = make_float4(0,0,0,0);
  for (int i = blockIdx.x*256 + t; i < Ecnt; i += gridDim.x*256) {
    float4 v = ((const float4*)ei)[i];
    s.x += v.x; s.y += v.y; s.z += v.z; s.w += v.w;
    q.x += v.x*v.x; q.y += v.y*v.y; q.z += v.z*v.z; q.w += v.w*v.w;
  }
  r1[t] = s; r2[t] = q; __syncthreads();
  for (int st = 128; st > 0; st >>= 1) {
    if (t < st) { r1[t] = f4add(r1[t], r1[t+st]); r2[t] = f4add(r2[t], r2[t+st]); }
    __syncthreads();
  }
  if (t == 0) {
    atomicAdd(&S[0], r1[0].x); atomicAdd(&S[1], r1[0].y);
    atomicAdd(&S[2], r1[0].z); atomicAdd(&S[3], r1[0].w);
    atomicAdd(&S[4], r2[0].x); atomicAdd(&S[5], r2[0].y);
    atomicAdd(&S[6], r2[0].z); atomicAdd(&S[7], r2[0].w);
  }
}

// ---- finalize edge stats (ddof=1 std) + softmax(layer_w) ----
__global__ void k_finalize_a(const float* __restrict__ S, const float* __restrict__ lw,
                             float* __restrict__ mu, float* __restrict__ sdinv,
                             float* __restrict__ wsm) {
  int t = threadIdx.x;
  if (t < 4) {
    float s = S[t], q = S[4+t];
    float m = s / (float)Ecnt;
    float var = (q - s*s/(float)Ecnt) / (float)(Ecnt - 1);
    mu[t] = m;
    sdinv[t] = rsqrtf(var);
  }
  if (t == 0) {
    float l0 = lw[0], l1 = lw[1], l2 = lw[2], l3 = lw[3];
    float mx = fmaxf(fmaxf(l0,l1), fmaxf(l2,l3));
    float e0 = expf(l0-mx), e1 = expf(l1-mx), e2 = expf(l2-mx), e3 = expf(l3-mx);
    float inv = 1.f/(e0+e1+e2+e3);
    wsm[0]=e0*inv; wsm[1]=e1*inv; wsm[2]=e2*inv; wsm[3]=e3*inv;
  }
}

// ---- batch stats of h = relu(z @ w1 + b1), both sides ----
__global__ void k_hstats(const float* __restrict__ ei, const float* __restrict__ w1,
                         const float* __restrict__ b1, const float* __restrict__ mu,
                         const float* __restrict__ sdinv,
                         float* __restrict__ hsum, float* __restrict__ hsq) {
  __shared__ float z[1024];
  int t = threadIdx.x;
  int e0 = blockIdx.x * 256;
  for (int i = 0; i < 4; ++i) z[i*256+t] = ei[e0*4 + i*256 + t];
  __syncthreads();
  int side = t >> 7, k = t & 127;
  float wa = w1[k], wb = w1[128+k], bb = b1[k];
  float m0 = mu[side*2], m1 = mu[side*2+1];
  float s0 = sdinv[side*2], s1 = sdinv[side*2+1];
  float sum = 0.f, sq = 0.f;
  for (int e = 0; e < 256; ++e) {
    float z0 = (z[e*4 + side*2]   - m0) * s0;
    float z1 = (z[e*4 + side*2+1] - m1) * s1;
    float h = fmaxf(z0*wa + z1*wb + bb, 0.f);
    sum += h; sq += h*h;
  }
  atomicAdd(&hsum[t], sum);
  atomicAdd(&hsq[t], sq);
}

// ---- fold BN into scale/shift: hn = h*scale + shift ----
__global__ void k_finalize_b(const float* __restrict__ hsum, const float* __restrict__ hsq,
                             const float* __restrict__ g, const float* __restrict__ b,
                             float* __restrict__ hscale, float* __restrict__ hshift) {
  int t = threadIdx.x;           // 256 = side*128+k
  int k = t & 127;
  float m = hsum[t] / (float)Ecnt;
  float var = hsq[t] / (float)Ecnt - m*m;
  float sc = g[k] * rsqrtf(var + 1e-5f);
  hscale[t] = sc;
  hshift[t] = b[k] - m*sc;
}

// ---- big edge kernel: o = hn @ w2 + b2 (both sides), cosine -> ew, deg atomics ----
// Phase-2 restructured: lane = output row (64 = 2 sides x 32 edges), wave =
// 32-column group. w2 row address is wave-uniform (readfirstlane) -> s_load
// SGPR broadcast on the SMEM pipe; hn read is one ds_read_b32/k at odd
// stride 129 (2-lane/bank aliasing = free). Cosine terms via __shfl_xor(32)
// (lanes e and e+32 hold o1/o2 same column slice), then small LDS reduce.
#define HNS 129

__global__ __launch_bounds__(256) void k_edge(
    const float* __restrict__ ei, const int* __restrict__ eidx,
    const float* __restrict__ w1, const float* __restrict__ b1,
    const float* __restrict__ mu, const float* __restrict__ sdinv,
    const float* __restrict__ hscale, const float* __restrict__ hshift,
    const float* __restrict__ w2, const float* __restrict__ b2,
    float* __restrict__ ew, float* __restrict__ deg) {
  __shared__ float zl[128];
  __shared__ float hn[64 * HNS];   // row = side*32 + e
  __shared__ float red[512];       // [wv][lane][2]
  int t = threadIdx.x;
  int e0 = blockIdx.x * 32;
  if (t < 32) ((float4*)zl)[t] = ((const float4*)ei)[e0 + t];
  __syncthreads();
  float mu0 = mu[0], mu1 = mu[1], mu2 = mu[2], mu3 = mu[3];
  float si0 = sdinv[0], si1 = sdinv[1], si2 = sdinv[2], si3 = sdinv[3];
  for (int it = 0; it < 16; ++it) {
    int idx = it*256 + t;
    int e = idx >> 7, k = idx & 127;
    float wa = w1[k], wb = w1[128+k], bb = b1[k];
    float za = (zl[e*4+0]-mu0)*si0, zb = (zl[e*4+1]-mu1)*si1;
    float zc = (zl[e*4+2]-mu2)*si2, zd = (zl[e*4+3]-mu3)*si3;
    float h1 = fmaxf(za*wa + zb*wb + bb, 0.f);
    float h2 = fmaxf(zc*wa + zd*wb + bb, 0.f);
    hn[e*HNS + k]      = h1*hscale[k]     + hshift[k];
    hn[(32+e)*HNS + k] = h2*hscale[128+k] + hshift[128+k];
  }
  __syncthreads();

  int lane = t & 63;               // output row r
  int wv = __builtin_amdgcn_readfirstlane(t >> 6);
  const float* w2u = w2 + wv * 32; // wave-uniform column base

  float acc[32];
  #pragma unroll
  for (int j = 0; j < 32; ++j) acc[j] = b2[wv*32 + j];

  const float* hp = &hn[lane * HNS];
  #pragma unroll 2
  for (int k = 0; k < 128; ++k) {
    float hv = hp[k];
    const float* wr = w2u + (size_t)k * 128;   // uniform -> s_load
    #pragma unroll
    for (int j4 = 0; j4 < 8; ++j4) {
      float4 w = *(const float4*)(wr + j4*4);
      acc[j4*4+0] += hv*w.x; acc[j4*4+1] += hv*w.y;
      acc[j4*4+2] += hv*w.z; acc[j4*4+3] += hv*w.w;
    }
  }

  // per-lane partials: d = sum_j o[r][j]*o[r^32][j], s = sum_j o[r][j]^2
  float d = 0.f, s = 0.f;
  #pragma unroll
  for (int j = 0; j < 32; ++j) {
    float o  = acc[j];
    float op = __shfl_xor(o, 32, 64);
    d += o*op; s += o*o;
  }
  red[((t >> 6)*64 + lane)*2 + 0] = d;
  red[((t >> 6)*64 + lane)*2 + 1] = s;
  __syncthreads();
  if (t < 32) {
    float dot = 0.f, q1 = 0.f, q2 = 0.f;
    #pragma unroll
    for (int v = 0; v < 4; ++v) {
      dot += red[(v*64 + t)*2 + 0];
      q1  += red[(v*64 + t)*2 + 1];
      q2  += red[(v*64 + t + 32)*2 + 1];
    }
    float nn = sqrtf(q1*q2);
    float c = dot / fmaxf(nn, 1e-8f);
    float w = 0.5f*(c + 1.f);
    ew[e0+t] = w;
    atomicAdd(&deg[eidx[Ecnt + e0 + t]], w);
  }
}

// ---- dinv = rsqrt(deg + 1)  (self-loop weight 1 folded in; deg>=1 always) ----
__global__ void k_dinv(const float* __restrict__ deg, float* __restrict__ dinv) {
  int n = blockIdx.x*256 + threadIdx.x;
  if (n < Ncnt) dinv[n] = rsqrtf(deg[n] + 1.0f);
}

// ---- layer-0 GEMM ----
#define G0_ROWS 64
#define G0_KC   128
#define G0_KSPLIT 8

__global__ __launch_bounds__(256) void k_gemm0(const float* __restrict__ emb,
                                               const float* __restrict__ w0,
                                               float* __restrict__ xw) {
  __shared__ float embL[G0_ROWS * 132];
  int t = threadIdx.x;
  int lane = t & 63, wv = t >> 6;
  int r0 = blockIdx.x * G0_ROWS;
  float acc[16];
  #pragma unroll
  for (int h = 0; h < 16; ++h) acc[h] = 0.f;

  for (int c = blockIdx.y; c * G0_KC < INF_; c += G0_KSPLIT) {
    int k0 = c * G0_KC;
    int klen = INF_ - k0; if (klen > G0_KC) klen = G0_KC;   // 128 or 60 (div by 4)
    __syncthreads();
    // stage 64 rows x klen floats, coalesced float4
    for (int i = t; i < G0_ROWS * (G0_KC/4); i += 256) {
      int rr = i >> 5;          // 32 float4 per row
      int ff = i & 31;
      float4 v = make_float4(0.f, 0.f, 0.f, 0.f);
      int gr = r0 + rr;
      if (gr >= Ncnt) gr = 0;   // valid address; result discarded at epilogue
      if (ff * 4 < klen) v = *(const float4*)(emb + (size_t)gr * INF_ + k0 + ff * 4);
      *(float4*)(embL + rr * 132 + ff * 4) = v;
    }
    __syncthreads();
    // wave wv computes k-quarter [wv*32, wv*32+32) (in float4 steps)
    int kqend = klen >> 2;
    int kqlo = wv * 8, kqhi = kqlo + 8;
    if (kqhi > kqend) kqhi = kqend;
    for (int kq = kqlo; kq < kqhi; ++kq) {
      float4 ev = *(const float4*)(embL + lane * 132 + kq * 4);
      const float* wr = w0 + (size_t)(k0 + kq * 4) * 16;   // wave-uniform -> s_load
      #pragma unroll
      for (int s = 0; s < 4; ++s) {
        float evs = (s == 0) ? ev.x : (s == 1) ? ev.y : (s == 2) ? ev.z : ev.w;
        #pragma unroll
        for (int h4 = 0; h4 < 4; ++h4) {
          float4 w = *(const float4*)(wr + s * 16 + h4 * 4);
          acc[h4*4+0] += evs * w.x; acc[h4*4+1] += evs * w.y;
          acc[h4*4+2] += evs * w.z; acc[h4*4+3] += evs * w.w;
        }
      }
    }
  }
  int gr = r0 + lane;
  if (gr < Ncnt) {
    #pragma unroll
    for (int h = 0; h < 16; ++h) atomicAdd(&xw[gr * 16 + h], acc[h]);
  }
}

// ---- scatter: xo[col] += dinv[row]*ew*dinv[col] * xw[row]  (+ self loops) ----
__global__ void k_scatter(const int* __restrict__ eidx, const float* __restrict__ ew,
                          const float* __restrict__ dinv, const float* __restrict__ xw,
                          float* __restrict__ xo) {
  int g = blockIdx.x*256 + threadIdx.x;
  if (g >= (Ecnt + Ncnt)*4) return;
  int ent = g >> 2, q = g & 3;
  int r, c; float w;
  if (ent < Ecnt) {
    r = eidx[ent]; c = eidx[Ecnt + ent];
    w = dinv[r] * ew[ent] * dinv[c];
  } else {
    int n = ent - Ecnt; r = n; c = n;
    float dv = dinv[n]; w = dv*dv;
  }
  float4 v = *(const float4*)(xw + r*16 + q*4);
  float* dst = xo + c*16 + q*4;
  atomicAdd(dst+0, w*v.x);
  atomicAdd(dst+1, w*v.y);
  atomicAdd(dst+2, w*v.z);
  atomicAdd(dst+3, w*v.w);
}

// ---- per-layer BN stats (per column sums over N) ----
__global__ void k_bnstats(const float* __restrict__ x, float* __restrict__ bsum,
                          float* __restrict__ bsq) {
  __shared__ float r1[256], r2[256];
  int t = threadIdx.x;
  float sum = 0.f, sq = 0.f;
  for (int i = blockIdx.x*256 + t; i < Ncnt*HID; i += gridDim.x*256) {
    float v = x[i]; sum += v; sq += v*v;
  }
  r1[t] = sum; r2[t] = sq; __syncthreads();
  for (int s = 128; s >= 16; s >>= 1) {
    if (t < s) { r1[t] += r1[t+s]; r2[t] += r2[t+s]; }
    __syncthreads();
  }
  if (t < 16) { atomicAdd(&bsum[t], r1[t]); atomicAdd(&bsq[t], r2[t]); }
}

// ---- apply BN + relu + residual (in place). gcn_b cancels through BN. ----
__global__ void k_apply(float* __restrict__ x, const float* __restrict__ prev,
                        const float* __restrict__ bsum, const float* __restrict__ bsq,
                        const float* __restrict__ g, const float* __restrict__ b) {
  int i = blockIdx.x*256 + threadIdx.x;      // grid 375 -> exactly 96000
  int c = i & 15;
  float m = bsum[c] * (1.f/Ncnt);
  float var = bsq[c] * (1.f/Ncnt) - m*m;
  float rs = rsqrtf(var + 1e-5f);
  float v = (x[i]-m)*rs*g[c] + b[c];
  v = fmaxf(v, 0.f);
  if (prev) v += 0.7f*prev[i];
  x[i] = v;
}

// ---- small 16x16 GEMM for layers 1..3 ----
__global__ void k_gemm_small(const float* __restrict__ xin, const float* __restrict__ wm,
                             float* __restrict__ xw) {
  __shared__ float lx[16][17], lw_[16][17];
  int t = threadIdx.x;
  int r = t >> 4, c = t & 15;
  lx[r][c]  = xin[(blockIdx.x*16 + r)*16 + c];
  lw_[r][c] = wm[r*16 + c];
  __syncthreads();
  float acc = 0.f;
  #pragma unroll
  for (int k = 0; k < 16; ++k) acc += lx[r][k] * lw_[k][c];
  xw[(blockIdx.x*16 + r)*16 + c] = acc;
}

// ---- final: out = (sum_i wsm[i]*x_i) @ proj_w + proj_b ----
__global__ void k_proj(const float* __restrict__ x0, const float* __restrict__ x1,
                       const float* __restrict__ x2, const float* __restrict__ x3,
                       const float* __restrict__ wsm, const float* __restrict__ pw,
                       const float* __restrict__ pb, float* __restrict__ out) {
  int n = blockIdx.x*256 + threadIdx.x;
  if (n >= Ncnt) return;
  float s0 = wsm[0], s1 = wsm[1], s2 = wsm[2], s3 = wsm[3];
  float a0 = pb[0], a1 = pb[1];
  #pragma unroll
  for (int h = 0; h < 16; ++h) {
    float e = s0*x0[n*16+h] + s1*x1[n*16+h] + s2*x2[n*16+h] + s3*x3[n*16+h];
    a0 += e * pw[h*2];
    a1 += e * pw[h*2+1];
  }
  out[n*2]   = a0;
  out[n*2+1] = a1;
}

extern "C" void kernel_launch(void* const* d_in, const int* in_sizes, int n_in,
                              void* d_out, int out_size, void* d_ws, size_t ws_size,
                              hipStream_t stream) {
  const float* emb   = (const float*)d_in[0];
  const int*   eidx  = (const int*)d_in[1];
  const float* einp  = (const float*)d_in[2];
  const float* e_w1  = (const float*)d_in[3];
  const float* e_b1  = (const float*)d_in[4];
  const float* e_bng = (const float*)d_in[5];
  const float* e_bnb = (const float*)d_in[6];
  const float* e_w2  = (const float*)d_in[7];
  const float* e_b2  = (const float*)d_in[8];
  const float* w0    = (const float*)d_in[9];
  const float* wrest = (const float*)d_in[10];
  // d_in[11] = gcn_b: provably cancels through training-mode BN (column shift)
  const float* bn_g  = (const float*)d_in[12];
  const float* bn_b  = (const float*)d_in[13];
  const float* lw    = (const float*)d_in[14];
  const float* pw    = (const float*)d_in[15];
  const float* pb    = (const float*)d_in[16];

  float* ws     = (float*)d_ws;
  float* S      = ws + OFF_SEDGE;
  float* hsum   = ws + OFF_HSUM;
  float* hsq    = ws + OFF_HSQ;
  float* deg    = ws + OFF_DEG;
  float* bnsum  = ws + OFF_BNSUM;
  float* bnsq   = ws + OFF_BNSQ;
  float* xw     = ws + OFF_XW;
  float* mu     = ws + OFF_MU;
  float* sdinv  = ws + OFF_SDINV;
  float* wsm    = ws + OFF_WSM;
  float* hscale = ws + OFF_HSCALE;
  float* hshift = ws + OFF_HSHIFT;
  float* dinv   = ws + OFF_DINV;
  float* ewb    = ws + OFF_EW;
  float* xb[4]  = { ws + OFF_XBUF, ws + OFF_XBUF + 96000,
                    ws + OFF_XBUF + 192000, ws + OFF_XBUF + 288000 };

  hipMemsetAsync(d_ws, 0, (size_t)ZERO_FLOATS * 4, stream);

  k_estats<<<188, 256, 0, stream>>>(einp, S);
  k_finalize_a<<<1, 64, 0, stream>>>(S, lw, mu, sdinv, wsm);
  k_hstats<<<750, 256, 0, stream>>>(einp, e_w1, e_b1, mu, sdinv, hsum, hsq);
  k_finalize_b<<<1, 256, 0, stream>>>(hsum, hsq, e_bng, e_bnb, hscale, hshift);
  k_edge<<<6000, 256, 0, stream>>>(einp, eidx, e_w1, e_b1, mu, sdinv,
                                   hscale, hshift, e_w2, e_b2, ewb, deg);
  k_dinv<<<24, 256, 0, stream>>>(deg, dinv);
  k_gemm0<<<dim3((Ncnt + G0_ROWS - 1)/G0_ROWS, G0_KSPLIT), 256, 0, stream>>>(emb, w0, xw);

  for (int l = 0; l < 4; ++l) {
    if (l > 0) k_gemm_small<<<375, 256, 0, stream>>>(xb[l-1], wrest + (l-1)*256, xw);
    k_scatter<<<3094, 256, 0, stream>>>(eidx, ewb, dinv, xw, xb[l]);
    k_bnstats<<<48, 256, 0, stream>>>(xb[l], bnsum + l*16, bnsq + l*16);
    k_apply<<<375, 256, 0, stream>>>(xb[l], (l > 0) ? xb[l-1] : (const float*)nullptr,
                                     bnsum + l*16, bnsq + l*16, bn_g + l*16, bn_b + l*16);
  }

  k_proj<<<24, 256, 0, stream>>>(xb[0], xb[1], xb[2], xb[3], wsm, pw, pb, (float*)d_out);
}